// Round 6
// baseline (508.409 us; speedup 1.0000x reference)
//
#include <hip/hip_runtime.h>
#include <hip/hip_fp16.h>

#define N_NODES 100000
#define N_EDGES 1600000
#define NBUCKET 196          // ceil(100000 / 512)
#define CAP     8960         // per-bucket capacity: mean 8163, sigma 90 -> +8.8 sigma
#define EPB     6250         // edges per block in partition (256 blocks)

typedef _Float16 half8 __attribute__((ext_vector_type(8)));
typedef float float4v __attribute__((ext_vector_type(4)));

// ---------------- partition edges into fixed-capacity bucket segments
// packed entry: (src << 9) | (dst & 511)  [src < 2^17, bucket-local dst < 2^9]
__launch_bounds__(256)
__global__ void k_partition(const int* __restrict__ src, const int* __restrict__ dst,
                            int* __restrict__ bcur, int* __restrict__ ebuf, int E) {
    __shared__ int hist[200];
    __shared__ int basebkt[200];
    const int tid = threadIdx.x;
    if (tid < 200) hist[tid] = 0;
    __syncthreads();
    const int e0 = blockIdx.x * EPB, e1 = min(e0 + EPB, E);
    for (int e = e0 + tid; e < e1; e += 256) atomicAdd(&hist[dst[e] >> 9], 1);
    __syncthreads();
    if (tid < NBUCKET) {
        int h = hist[tid];
        basebkt[tid] = tid * CAP + (h ? atomicAdd(&bcur[tid], h) : 0);
    }
    __syncthreads();
    if (tid < 200) hist[tid] = 0;
    __syncthreads();
    for (int e = e0 + tid; e < e1; e += 256) {
        int d = dst[e];
        int bk = d >> 9;
        int o = atomicAdd(&hist[bk], 1);
        ebuf[basebkt[bk] + o] = (src[e] << 9) | (d & 511);
    }
}

// ---------------- per-bucket counting sort -> deg, stv, dinv, adj (bucketed layout)
__launch_bounds__(256)
__global__ void k_bsort(const int* __restrict__ ebuf, const int* __restrict__ bcur,
                        int* __restrict__ adj, int* __restrict__ stv,
                        int* __restrict__ deg, float* __restrict__ dinv, int N) {
    __shared__ int cnt[512];
    __shared__ int offs[512];
    const int b = blockIdx.x;
    const int tid = threadIdx.x;
    const int base = b * CAP;
    const int n_b = min(bcur[b], CAP);
    const int node0 = b << 9;
    cnt[tid] = 0; cnt[tid + 256] = 0;
    __syncthreads();
    for (int i = tid; i < n_b; i += 256)
        atomicAdd(&cnt[ebuf[base + i] & 511], 1);
    __syncthreads();
    if (tid < 64) {  // wave-0 exclusive scan of 512
        int v[8], tot = 0;
#pragma unroll
        for (int j = 0; j < 8; ++j) { int t = cnt[tid * 8 + j]; v[j] = tot; tot += t; }
        int inc = tot;
#pragma unroll
        for (int d = 1; d < 64; d <<= 1) {
            int u = __shfl_up(inc, d, 64);
            if (tid >= d) inc += u;
        }
        const int excl = inc - tot;
#pragma unroll
        for (int j = 0; j < 8; ++j) offs[tid * 8 + j] = excl + v[j];
    }
    __syncthreads();
#pragma unroll
    for (int h = 0; h < 2; ++h) {
        int local = tid + h * 256;
        int node = node0 + local;
        if (node < N) {
            stv[node] = base + offs[local];
            deg[node] = cnt[local];
            dinv[node] = rsqrtf((float)(cnt[local] + 1));
        }
    }
    __syncthreads();
    for (int i = tid; i < n_b; i += 256) {  // offs doubles as cursor
        int pk = ebuf[base + i];
        int pos = atomicAdd(&offs[pk & 511], 1);
        adj[base + pos] = pk >> 9;
    }
}

// ---------------- all three W -> fp16 B-fragment swizzles in one kernel
// frag (nt,kblk): lane l holds W[kblk*32 + (l>>4)*8 + j][nt*16 + (l&15)], j=0..7
__global__ void k_wswz_all(const float* __restrict__ W1, const float* __restrict__ W2,
                           const float* __restrict__ W3, _Float16* __restrict__ wz1,
                           _Float16* __restrict__ wz2, _Float16* __restrict__ wz3) {
    int t = blockIdx.x * 256 + threadIdx.x;
    const float* W; _Float16* wsz; int BN;
    if (t < 2048)      { W = W1; wsz = wz1; BN = 128; }
    else if (t < 4096) { W = W2; wsz = wz2; BN = 128; t -= 2048; }
    else if (t < 5120) { W = W3; wsz = wz3; BN = 64;  t -= 4096; }
    else return;
    const int l = t & 63;
    const int kblk = (t >> 6) & 3;
    const int nt = t >> 8;
    const int krow = kblk * 32 + ((l >> 4) << 3);
    const int col = nt * 16 + (l & 15);
    _Float16 v[8];
#pragma unroll
    for (int j = 0; j < 8; ++j) v[j] = (_Float16)W[(krow + j) * BN + col];
    *(uint4*)&wsz[t << 3] = *(uint4*)v;
}

// ---------------- MFMA GEMM: tp[i][:] = fp16( dinv[i] * (X[i][:] @ W) ), K=128
template <int BN, bool AFP16>
__launch_bounds__(256, 4)
__global__ void k_gemm_mfma(const void* __restrict__ Xv, const _Float16* __restrict__ wsz,
                            const float* __restrict__ dinv, __half* __restrict__ out, int N) {
    constexpr int NT = BN / 16;               // n-tiles per wave: 8 or 4
    constexpr int PAD = 8;
    __shared__ __align__(16) _Float16 smem[BN * 128];  // B frags; reused for epilogue

    const int tid = threadIdx.x;
    for (int i = tid; i < BN * 16; i += 256)
        *(uint4*)&smem[i << 3] = *(const uint4*)&wsz[i << 3];

    const int w = tid >> 6;
    const int lane = tid & 63;
    const int q = lane >> 4;
    const int m = lane & 15;
    const int row0 = blockIdx.x * 64;
    const int arow = row0 + w * 16 + m;
    const int arowc = arow < N ? arow : N - 1;

    float4v acc[NT];
#pragma unroll
    for (int nt = 0; nt < NT; ++nt) acc[nt] = (float4v){0.f, 0.f, 0.f, 0.f};

    __syncthreads();

#pragma unroll
    for (int kblk = 0; kblk < 4; ++kblk) {
        half8 af;
        if constexpr (AFP16) {
            const _Float16* A = (const _Float16*)Xv + (size_t)arowc * 128 + (q << 3);
            af = *(const half8*)(A + kblk * 32);
        } else {
            const float* A = (const float*)Xv + (size_t)arowc * 128 + (q << 3);
            float4 a0 = *(const float4*)(A + kblk * 32);
            float4 a1 = *(const float4*)(A + kblk * 32 + 4);
            af[0] = (_Float16)a0.x; af[1] = (_Float16)a0.y;
            af[2] = (_Float16)a0.z; af[3] = (_Float16)a0.w;
            af[4] = (_Float16)a1.x; af[5] = (_Float16)a1.y;
            af[6] = (_Float16)a1.z; af[7] = (_Float16)a1.w;
        }
#pragma unroll
        for (int nt = 0; nt < NT; ++nt) {
            half8 bf = *(const half8*)&smem[(((nt << 2) + kblk) << 9) + (lane << 3)];
            acc[nt] = __builtin_amdgcn_mfma_f32_16x16x32_f16(af, bf, acc[nt], 0, 0, 0);
        }
    }

    float s[4];
#pragma unroll
    for (int r = 0; r < 4; ++r) {
        int rr = row0 + w * 16 + q * 4 + r;
        s[r] = dinv[rr < N ? rr : N - 1];
    }
    __syncthreads();  // all B reads done before smem reuse
    _Float16* eb = smem;
#pragma unroll
    for (int nt = 0; nt < NT; ++nt)
#pragma unroll
        for (int r = 0; r < 4; ++r)
            eb[(w * 16 + q * 4 + r) * (BN + PAD) + nt * 16 + m] = (_Float16)(acc[nt][r] * s[r]);
    __syncthreads();
    constexpr int CPR = BN / 8;
    for (int i = tid; i < 64 * CPR; i += 256) {
        int row = i / CPR;
        int cf = (i % CPR) * 8;
        if (row0 + row < N)
            *(uint4*)&out[(size_t)(row0 + row) * BN + cf] = *(uint4*)&eb[row * (BN + PAD) + cf];
    }
}

// ---------------- half-width aggregation pass for d=128 layers
// Processes columns [h*64, h*64+64). Two sequential passes shrink the gather
// working set 25.6->12.8 MB (per-XCD reuse gap 3.2->1.6 MB vs 4 MB L2).
template <bool RELU>
__launch_bounds__(256)
__global__ void k_agg_half(const __half* __restrict__ tp, const int* __restrict__ adj,
                           const int* __restrict__ startv, const int* __restrict__ deg,
                           const float* __restrict__ dinv, const float* __restrict__ b,
                           _Float16* __restrict__ out, int N, int h) {
    const int node = (blockIdx.x << 2) + (threadIdx.x >> 6);
    const int lane = threadIdx.x & 63;
    if (node >= N) return;
    const int s = startv[node];
    const int cnt = deg[node];
    const float di = dinv[node];
    const __half* col = tp + h * 64 + lane;   // column slice base

    float acc = __half2float(col[(size_t)node * 128]);  // self-loop
    int e = 0;
    for (; e + 8 <= cnt; e += 8) {
        int j[8];
#pragma unroll
        for (int u = 0; u < 8; ++u) j[u] = adj[s + e + u];
        __half r[8];
#pragma unroll
        for (int u = 0; u < 8; ++u) r[u] = col[(size_t)j[u] * 128];
#pragma unroll
        for (int u = 0; u < 8; ++u) acc += __half2float(r[u]);
    }
    for (; e < cnt; ++e) acc += __half2float(col[(size_t)adj[s + e] * 128]);
    float o = di * acc + b[h * 64 + lane];
    if (RELU) o = fmaxf(o, 0.f);
    out[(size_t)node * 128 + h * 64 + lane] = (_Float16)o;
}

// ---------------- final d=64 aggregation (fp32 out)
__launch_bounds__(256)
__global__ void k_agg64(const __half* __restrict__ tp, const int* __restrict__ adj,
                        const int* __restrict__ startv, const int* __restrict__ deg,
                        const float* __restrict__ dinv, const float* __restrict__ b,
                        float* __restrict__ out, int N) {
    const int node = (blockIdx.x << 2) + (threadIdx.x >> 6);
    const int lane = threadIdx.x & 63;
    if (node >= N) return;
    const int s = startv[node];
    const int cnt = deg[node];
    const float di = dinv[node];

    float acc = __half2float(tp[(size_t)node * 64 + lane]);  // self-loop
    int e = 0;
    for (; e + 8 <= cnt; e += 8) {
        int j[8];
#pragma unroll
        for (int u = 0; u < 8; ++u) j[u] = adj[s + e + u];
        __half r[8];
#pragma unroll
        for (int u = 0; u < 8; ++u) r[u] = tp[(size_t)j[u] * 64 + lane];
#pragma unroll
        for (int u = 0; u < 8; ++u) acc += __half2float(r[u]);
    }
    for (; e < cnt; ++e) acc += __half2float(tp[(size_t)adj[s + e] * 64 + lane]);
    float o = di * acc + b[lane];
    out[(size_t)node * 64 + lane] = o;
}

extern "C" void kernel_launch(void* const* d_in, const int* in_sizes, int n_in,
                              void* d_out, int out_size, void* d_ws, size_t ws_size,
                              hipStream_t stream) {
    const float* x  = (const float*)d_in[0];
    const int*   ei = (const int*)d_in[1];
    const float* W1 = (const float*)d_in[2];
    const float* b1 = (const float*)d_in[3];
    const float* W2 = (const float*)d_in[4];
    const float* b2 = (const float*)d_in[5];
    const float* W3 = (const float*)d_in[6];
    const float* b3 = (const float*)d_in[7];
    float* out = (float*)d_out;
    const int* src = ei;            // edge_index[0]
    const int* dst = ei + N_EDGES;  // edge_index[1]

    char* p = (char*)d_ws;
    __half* tp      = (__half*)p;    p += (size_t)N_NODES * 128 * 2;   // 25.6 MB
    _Float16* hbuf  = (_Float16*)p;  p += (size_t)N_NODES * 128 * 2;   // 25.6 MB
    int*   deg  = (int*)p;    p += (size_t)N_NODES * 4;
    float* dinv = (float*)p;  p += (size_t)N_NODES * 4;
    int*   stv  = (int*)p;    p += (size_t)N_NODES * 4;
    int*   bCur = (int*)p;    p += 1024;                               // bucket fill counts
    int*   adj  = (int*)p;    p += (size_t)NBUCKET * CAP * 4 + 16384;  // 7.0 MB bucketed
    _Float16* wz1 = (_Float16*)p; p += 16384 * 2;                      // 32 KB
    _Float16* wz2 = (_Float16*)p; p += 16384 * 2;                      // 32 KB
    _Float16* wz3 = (_Float16*)p; p += 8192 * 2;                       // 16 KB
    size_t need = (size_t)(p - (char*)d_ws);
    if (ws_size < need) return;  // visible failure rather than OOB

    int* ebuf = (int*)tp;  // 7.0 MB alias; tp not live until layer-1 GEMM

    hipMemsetAsync(bCur, 0, 1024, stream);

    k_wswz_all<<<20, 256, 0, stream>>>(W1, W2, W3, wz1, wz2, wz3);
    k_partition<<<256, 256, 0, stream>>>(src, dst, bCur, ebuf, N_EDGES);
    k_bsort<<<NBUCKET, 256, 0, stream>>>(ebuf, bCur, adj, stv, deg, dinv, N_NODES);

    const int gb = (N_NODES + 63) / 64;
    const int ab = (N_NODES + 3) / 4;
    // layer 1: relu(agg(x@W1) + b1) -> fp16 hbuf (two half-dim passes)
    k_gemm_mfma<128, false><<<gb, 256, 0, stream>>>(x, wz1, dinv, tp, N_NODES);
    k_agg_half<true><<<ab, 256, 0, stream>>>(tp, adj, stv, deg, dinv, b1, hbuf, N_NODES, 0);
    k_agg_half<true><<<ab, 256, 0, stream>>>(tp, adj, stv, deg, dinv, b1, hbuf, N_NODES, 1);
    // layer 2
    k_gemm_mfma<128, true><<<gb, 256, 0, stream>>>(hbuf, wz2, dinv, tp, N_NODES);
    k_agg_half<true><<<ab, 256, 0, stream>>>(tp, adj, stv, deg, dinv, b2, hbuf, N_NODES, 0);
    k_agg_half<true><<<ab, 256, 0, stream>>>(tp, adj, stv, deg, dinv, b2, hbuf, N_NODES, 1);
    // layer 3: agg(h@W3) + b3 (no relu) -> fp32 out
    k_gemm_mfma<64, true><<<gb, 256, 0, stream>>>(hbuf, wz3, dinv, tp, N_NODES);
    k_agg64<<<ab, 256, 0, stream>>>(tp, adj, stv, deg, dinv, b3, out, N_NODES);
}

// Round 7
// 385.109 us; speedup vs baseline: 1.3202x; 1.3202x over previous
//
#include <hip/hip_runtime.h>
#include <hip/hip_fp16.h>

#define N_NODES 100000
#define N_EDGES 1600000
#define NBUCKET 196          // ceil(100000 / 512)
#define CAP     8960         // per-bucket capacity: mean 8163, sigma 90 -> +8.8 sigma
#define EPB     6250         // edges per block in partition (256 blocks)

typedef _Float16 half8 __attribute__((ext_vector_type(8)));
typedef float float4v __attribute__((ext_vector_type(4)));

// ---------------- partition edges into fixed-capacity bucket segments
// packed entry: (src << 9) | (dst & 511)  [src < 2^17, bucket-local dst < 2^9]
__launch_bounds__(256)
__global__ void k_partition(const int* __restrict__ src, const int* __restrict__ dst,
                            int* __restrict__ bcur, int* __restrict__ ebuf, int E) {
    __shared__ int hist[200];
    __shared__ int basebkt[200];
    const int tid = threadIdx.x;
    if (tid < 200) hist[tid] = 0;
    __syncthreads();
    const int e0 = blockIdx.x * EPB, e1 = min(e0 + EPB, E);
    for (int e = e0 + tid; e < e1; e += 256) atomicAdd(&hist[dst[e] >> 9], 1);
    __syncthreads();
    if (tid < NBUCKET) {
        int h = hist[tid];
        basebkt[tid] = tid * CAP + (h ? atomicAdd(&bcur[tid], h) : 0);
    }
    __syncthreads();
    if (tid < 200) hist[tid] = 0;
    __syncthreads();
    for (int e = e0 + tid; e < e1; e += 256) {
        int d = dst[e];
        int bk = d >> 9;
        int o = atomicAdd(&hist[bk], 1);
        ebuf[basebkt[bk] + o] = (src[e] << 9) | (d & 511);
    }
}

// ---------------- per-bucket in-place counting sort by coarse src (src>>9)
// After this, k_bsort emits each node's adjacency approx. src-ascending ->
// concurrent agg waves sweep src-space together -> L2-resident gather window.
__launch_bounds__(256)
__global__ void k_srcsort(int* __restrict__ ebuf, const int* __restrict__ bcur) {
    __shared__ int buf[CAP];      // 35.8 KB bucket copy
    __shared__ int cnt[256];
    __shared__ int offs[256];
    const int b = blockIdx.x;
    const int tid = threadIdx.x;
    const int base = b * CAP;
    const int n_b = min(bcur[b], CAP);
    if (tid < 256) cnt[tid] = 0;
    __syncthreads();
    for (int i = tid; i < n_b; i += 256) {
        int v = ebuf[base + i];
        buf[i] = v;
        atomicAdd(&cnt[(v >> 18) & 255], 1);   // (src>>9) <= 195
    }
    __syncthreads();
    if (tid < 64) {  // wave-0 exclusive scan of 256 bins
        int v[4], tot = 0;
#pragma unroll
        for (int j = 0; j < 4; ++j) { int t = cnt[tid * 4 + j]; v[j] = tot; tot += t; }
        int inc = tot;
#pragma unroll
        for (int d = 1; d < 64; d <<= 1) {
            int u = __shfl_up(inc, d, 64);
            if (tid >= d) inc += u;
        }
        const int excl = inc - tot;
#pragma unroll
        for (int j = 0; j < 4; ++j) offs[tid * 4 + j] = excl + v[j];
    }
    __syncthreads();
    for (int i = tid; i < n_b; i += 256) {
        int v = buf[i];
        int pos = atomicAdd(&offs[(v >> 18) & 255], 1);
        ebuf[base + pos] = v;
    }
}

// ---------------- per-bucket counting sort -> deg, stv, dinv, adj (bucketed layout)
__launch_bounds__(256)
__global__ void k_bsort(const int* __restrict__ ebuf, const int* __restrict__ bcur,
                        int* __restrict__ adj, int* __restrict__ stv,
                        int* __restrict__ deg, float* __restrict__ dinv, int N) {
    __shared__ int cnt[512];
    __shared__ int offs[512];
    const int b = blockIdx.x;
    const int tid = threadIdx.x;
    const int base = b * CAP;
    const int n_b = min(bcur[b], CAP);
    const int node0 = b << 9;
    cnt[tid] = 0; cnt[tid + 256] = 0;
    __syncthreads();
    for (int i = tid; i < n_b; i += 256)
        atomicAdd(&cnt[ebuf[base + i] & 511], 1);
    __syncthreads();
    if (tid < 64) {  // wave-0 exclusive scan of 512
        int v[8], tot = 0;
#pragma unroll
        for (int j = 0; j < 8; ++j) { int t = cnt[tid * 8 + j]; v[j] = tot; tot += t; }
        int inc = tot;
#pragma unroll
        for (int d = 1; d < 64; d <<= 1) {
            int u = __shfl_up(inc, d, 64);
            if (tid >= d) inc += u;
        }
        const int excl = inc - tot;
#pragma unroll
        for (int j = 0; j < 8; ++j) offs[tid * 8 + j] = excl + v[j];
    }
    __syncthreads();
#pragma unroll
    for (int h = 0; h < 2; ++h) {
        int local = tid + h * 256;
        int node = node0 + local;
        if (node < N) {
            stv[node] = base + offs[local];
            deg[node] = cnt[local];
            dinv[node] = rsqrtf((float)(cnt[local] + 1));
        }
    }
    __syncthreads();
    for (int i = tid; i < n_b; i += 256) {  // offs doubles as cursor
        int pk = ebuf[base + i];
        int pos = atomicAdd(&offs[pk & 511], 1);
        adj[base + pos] = pk >> 9;
    }
}

// ---------------- all three W -> fp16 B-fragment swizzles + bCur zeroing
__global__ void k_wswz_all(const float* __restrict__ W1, const float* __restrict__ W2,
                           const float* __restrict__ W3, _Float16* __restrict__ wz1,
                           _Float16* __restrict__ wz2, _Float16* __restrict__ wz3,
                           int* __restrict__ bcur) {
    if (blockIdx.x == 0) bcur[threadIdx.x] = 0;   // 256 ints
    int t = blockIdx.x * 256 + threadIdx.x;
    const float* W; _Float16* wsz; int BN;
    if (t < 2048)      { W = W1; wsz = wz1; BN = 128; }
    else if (t < 4096) { W = W2; wsz = wz2; BN = 128; t -= 2048; }
    else if (t < 5120) { W = W3; wsz = wz3; BN = 64;  t -= 4096; }
    else return;
    const int l = t & 63;
    const int kblk = (t >> 6) & 3;
    const int nt = t >> 8;
    const int krow = kblk * 32 + ((l >> 4) << 3);
    const int col = nt * 16 + (l & 15);
    _Float16 v[8];
#pragma unroll
    for (int j = 0; j < 8; ++j) v[j] = (_Float16)W[(krow + j) * BN + col];
    *(uint4*)&wsz[t << 3] = *(uint4*)v;
}

// ---------------- MFMA GEMM: tp[i][:] = fp16( dinv[i] * (X[i][:] @ W) ), K=128
template <int BN, bool AFP16>
__launch_bounds__(256, 4)
__global__ void k_gemm_mfma(const void* __restrict__ Xv, const _Float16* __restrict__ wsz,
                            const float* __restrict__ dinv, __half* __restrict__ out, int N) {
    constexpr int NT = BN / 16;
    constexpr int PAD = 8;
    __shared__ __align__(16) _Float16 smem[BN * 128];  // B frags; reused for epilogue

    const int tid = threadIdx.x;
    for (int i = tid; i < BN * 16; i += 256)
        *(uint4*)&smem[i << 3] = *(const uint4*)&wsz[i << 3];

    const int w = tid >> 6;
    const int lane = tid & 63;
    const int q = lane >> 4;
    const int m = lane & 15;
    const int row0 = blockIdx.x * 64;
    const int arow = row0 + w * 16 + m;
    const int arowc = arow < N ? arow : N - 1;

    float4v acc[NT];
#pragma unroll
    for (int nt = 0; nt < NT; ++nt) acc[nt] = (float4v){0.f, 0.f, 0.f, 0.f};

    __syncthreads();

#pragma unroll
    for (int kblk = 0; kblk < 4; ++kblk) {
        half8 af;
        if constexpr (AFP16) {
            const _Float16* A = (const _Float16*)Xv + (size_t)arowc * 128 + (q << 3);
            af = *(const half8*)(A + kblk * 32);
        } else {
            const float* A = (const float*)Xv + (size_t)arowc * 128 + (q << 3);
            float4 a0 = *(const float4*)(A + kblk * 32);
            float4 a1 = *(const float4*)(A + kblk * 32 + 4);
            af[0] = (_Float16)a0.x; af[1] = (_Float16)a0.y;
            af[2] = (_Float16)a0.z; af[3] = (_Float16)a0.w;
            af[4] = (_Float16)a1.x; af[5] = (_Float16)a1.y;
            af[6] = (_Float16)a1.z; af[7] = (_Float16)a1.w;
        }
#pragma unroll
        for (int nt = 0; nt < NT; ++nt) {
            half8 bf = *(const half8*)&smem[(((nt << 2) + kblk) << 9) + (lane << 3)];
            acc[nt] = __builtin_amdgcn_mfma_f32_16x16x32_f16(af, bf, acc[nt], 0, 0, 0);
        }
    }

    float s[4];
#pragma unroll
    for (int r = 0; r < 4; ++r) {
        int rr = row0 + w * 16 + q * 4 + r;
        s[r] = dinv[rr < N ? rr : N - 1];
    }
    __syncthreads();  // all B reads done before smem reuse
    _Float16* eb = smem;
#pragma unroll
    for (int nt = 0; nt < NT; ++nt)
#pragma unroll
        for (int r = 0; r < 4; ++r)
            eb[(w * 16 + q * 4 + r) * (BN + PAD) + nt * 16 + m] = (_Float16)(acc[nt][r] * s[r]);
    __syncthreads();
    constexpr int CPR = BN / 8;
    for (int i = tid; i < 64 * CPR; i += 256) {
        int row = i / CPR;
        int cf = (i % CPR) * 8;
        if (row0 + row < N)
            *(uint4*)&out[(size_t)(row0 + row) * BN + cf] = *(uint4*)&eb[row * (BN + PAD) + cf];
    }
}

// ---------------- d=128 aggregation: one wave per node, 2 edges per wave-load
// lanes 0-31 even edges, 32-63 odd edges; each lane 8 B (4 cols); shfl_xor(32) combine.
template <bool RELU>
__launch_bounds__(256)
__global__ void k_agg128(const __half* __restrict__ tp, const int* __restrict__ adj,
                         const int* __restrict__ startv, const int* __restrict__ deg,
                         const float* __restrict__ dinv, const float* __restrict__ bias,
                         _Float16* __restrict__ out, int N) {
    const int node = (blockIdx.x << 2) + (threadIdx.x >> 6);
    const int lane = threadIdx.x & 63;
    if (node >= N) return;
    const int s = startv[node];
    const int cnt = deg[node];
    const float di = dinv[node];
    const int hid = lane >> 5;
    const int sl = lane & 31;
    const uint2* rowb = (const uint2*)tp;   // row stride = 32 uint2 (256 B)

    float4 acc = {0.f, 0.f, 0.f, 0.f};
    if (hid == 0) {  // self-loop once
        uint2 v = rowb[(size_t)node * 32 + sl];
        float2 f0 = __half22float2(*(__half2*)&v.x);
        float2 f1 = __half22float2(*(__half2*)&v.y);
        acc.x += f0.x; acc.y += f0.y; acc.z += f1.x; acc.w += f1.y;
    }
    int e = 0;
    for (; e + 8 <= cnt; e += 8) {
        int j[4];
#pragma unroll
        for (int u = 0; u < 4; ++u) j[u] = adj[s + e + 2 * u + hid];
        uint2 v[4];
#pragma unroll
        for (int u = 0; u < 4; ++u) v[u] = rowb[(size_t)j[u] * 32 + sl];
#pragma unroll
        for (int u = 0; u < 4; ++u) {
            float2 f0 = __half22float2(*(__half2*)&v[u].x);
            float2 f1 = __half22float2(*(__half2*)&v[u].y);
            acc.x += f0.x; acc.y += f0.y; acc.z += f1.x; acc.w += f1.y;
        }
    }
    for (; e + 2 <= cnt; e += 2) {
        int j = adj[s + e + hid];
        uint2 v = rowb[(size_t)j * 32 + sl];
        float2 f0 = __half22float2(*(__half2*)&v.x);
        float2 f1 = __half22float2(*(__half2*)&v.y);
        acc.x += f0.x; acc.y += f0.y; acc.z += f1.x; acc.w += f1.y;
    }
    if (e < cnt && hid == 0) {  // odd tail
        int j = adj[s + e];
        uint2 v = rowb[(size_t)j * 32 + sl];
        float2 f0 = __half22float2(*(__half2*)&v.x);
        float2 f1 = __half22float2(*(__half2*)&v.y);
        acc.x += f0.x; acc.y += f0.y; acc.z += f1.x; acc.w += f1.y;
    }
    acc.x += __shfl_xor(acc.x, 32);
    acc.y += __shfl_xor(acc.y, 32);
    acc.z += __shfl_xor(acc.z, 32);
    acc.w += __shfl_xor(acc.w, 32);
    if (hid == 0) {
        float4 bb = *(const float4*)&bias[sl * 4];
        float o0 = di * acc.x + bb.x, o1 = di * acc.y + bb.y;
        float o2 = di * acc.z + bb.z, o3 = di * acc.w + bb.w;
        if (RELU) {
            o0 = fmaxf(o0, 0.f); o1 = fmaxf(o1, 0.f);
            o2 = fmaxf(o2, 0.f); o3 = fmaxf(o3, 0.f);
        }
        _Float16 ov[4] = {(_Float16)o0, (_Float16)o1, (_Float16)o2, (_Float16)o3};
        *(uint2*)&out[(size_t)node * 128 + sl * 4] = *(uint2*)ov;
    }
}

// ---------------- d=64 aggregation (fp32 out): 2 edges per wave-load
__launch_bounds__(256)
__global__ void k_agg64(const __half* __restrict__ tp, const int* __restrict__ adj,
                        const int* __restrict__ startv, const int* __restrict__ deg,
                        const float* __restrict__ dinv, const float* __restrict__ bias,
                        float* __restrict__ out, int N) {
    const int node = (blockIdx.x << 2) + (threadIdx.x >> 6);
    const int lane = threadIdx.x & 63;
    if (node >= N) return;
    const int s = startv[node];
    const int cnt = deg[node];
    const float di = dinv[node];
    const int hid = lane >> 5;
    const int sl = lane & 31;
    const __half2* rowb = (const __half2*)tp;  // row stride = 32 half2 (128 B)

    float2 acc = {0.f, 0.f};
    if (hid == 0) {  // self-loop
        float2 f = __half22float2(rowb[(size_t)node * 32 + sl]);
        acc.x += f.x; acc.y += f.y;
    }
    int e = 0;
    for (; e + 8 <= cnt; e += 8) {
        int j[4];
#pragma unroll
        for (int u = 0; u < 4; ++u) j[u] = adj[s + e + 2 * u + hid];
        __half2 v[4];
#pragma unroll
        for (int u = 0; u < 4; ++u) v[u] = rowb[(size_t)j[u] * 32 + sl];
#pragma unroll
        for (int u = 0; u < 4; ++u) {
            float2 f = __half22float2(v[u]);
            acc.x += f.x; acc.y += f.y;
        }
    }
    for (; e + 2 <= cnt; e += 2) {
        float2 f = __half22float2(rowb[(size_t)adj[s + e + hid] * 32 + sl]);
        acc.x += f.x; acc.y += f.y;
    }
    if (e < cnt && hid == 0) {
        float2 f = __half22float2(rowb[(size_t)adj[s + e] * 32 + sl]);
        acc.x += f.x; acc.y += f.y;
    }
    acc.x += __shfl_xor(acc.x, 32);
    acc.y += __shfl_xor(acc.y, 32);
    if (hid == 0) {
        float2 bb = *(const float2*)&bias[sl * 2];
        float2 o = {di * acc.x + bb.x, di * acc.y + bb.y};
        *(float2*)&out[(size_t)node * 64 + sl * 2] = o;
    }
}

extern "C" void kernel_launch(void* const* d_in, const int* in_sizes, int n_in,
                              void* d_out, int out_size, void* d_ws, size_t ws_size,
                              hipStream_t stream) {
    const float* x  = (const float*)d_in[0];
    const int*   ei = (const int*)d_in[1];
    const float* W1 = (const float*)d_in[2];
    const float* b1 = (const float*)d_in[3];
    const float* W2 = (const float*)d_in[4];
    const float* b2 = (const float*)d_in[5];
    const float* W3 = (const float*)d_in[6];
    const float* b3 = (const float*)d_in[7];
    float* out = (float*)d_out;
    const int* src = ei;            // edge_index[0]
    const int* dst = ei + N_EDGES;  // edge_index[1]

    char* p = (char*)d_ws;
    __half* tp      = (__half*)p;    p += (size_t)N_NODES * 128 * 2;   // 25.6 MB
    _Float16* hbuf  = (_Float16*)p;  p += (size_t)N_NODES * 128 * 2;   // 25.6 MB
    int*   deg  = (int*)p;    p += (size_t)N_NODES * 4;
    float* dinv = (float*)p;  p += (size_t)N_NODES * 4;
    int*   stv  = (int*)p;    p += (size_t)N_NODES * 4;
    int*   bCur = (int*)p;    p += 1024;                               // bucket fill counts
    int*   adj  = (int*)p;    p += (size_t)NBUCKET * CAP * 4 + 16384;  // 7.0 MB bucketed
    _Float16* wz1 = (_Float16*)p; p += 16384 * 2;                      // 32 KB
    _Float16* wz2 = (_Float16*)p; p += 16384 * 2;                      // 32 KB
    _Float16* wz3 = (_Float16*)p; p += 8192 * 2;                       // 16 KB
    size_t need = (size_t)(p - (char*)d_ws);
    if (ws_size < need) return;  // visible failure rather than OOB

    int* ebuf = (int*)tp;  // 7.0 MB alias; tp not live until layer-1 GEMM

    k_wswz_all<<<20, 256, 0, stream>>>(W1, W2, W3, wz1, wz2, wz3, bCur);
    k_partition<<<256, 256, 0, stream>>>(src, dst, bCur, ebuf, N_EDGES);
    k_srcsort<<<NBUCKET, 256, 0, stream>>>(ebuf, bCur);
    k_bsort<<<NBUCKET, 256, 0, stream>>>(ebuf, bCur, adj, stv, deg, dinv, N_NODES);

    const int gb = (N_NODES + 63) / 64;
    const int ab = (N_NODES + 3) / 4;
    // layer 1: relu(agg(x@W1) + b1) -> fp16 hbuf
    k_gemm_mfma<128, false><<<gb, 256, 0, stream>>>(x, wz1, dinv, tp, N_NODES);
    k_agg128<true><<<ab, 256, 0, stream>>>(tp, adj, stv, deg, dinv, b1, hbuf, N_NODES);
    // layer 2
    k_gemm_mfma<128, true><<<gb, 256, 0, stream>>>(hbuf, wz2, dinv, tp, N_NODES);
    k_agg128<true><<<ab, 256, 0, stream>>>(tp, adj, stv, deg, dinv, b2, hbuf, N_NODES);
    // layer 3: agg(h@W3) + b3 (no relu) -> fp32 out
    k_gemm_mfma<64, true><<<gb, 256, 0, stream>>>(hbuf, wz3, dinv, tp, N_NODES);
    k_agg64<<<ab, 256, 0, stream>>>(tp, adj, stv, deg, dinv, b3, out, N_NODES);
}

// Round 8
// 360.843 us; speedup vs baseline: 1.4089x; 1.0672x over previous
//
#include <hip/hip_runtime.h>
#include <hip/hip_fp16.h>

#define N_NODES 100000
#define N_EDGES 1600000
#define NBUCKET 196          // ceil(100000 / 512)
#define CAP     8960         // per-bucket capacity: mean 8163, sigma 90 -> +8.8 sigma
#define EPB     6250         // edges per block in partition (256 blocks)

typedef _Float16 half8 __attribute__((ext_vector_type(8)));
typedef float float4v __attribute__((ext_vector_type(4)));

// ---------------- partition edges into fixed-capacity bucket segments
// packed entry: (src << 9) | (dst & 511)  [src < 2^17, bucket-local dst < 2^9]
__launch_bounds__(256)
__global__ void k_partition(const int* __restrict__ src, const int* __restrict__ dst,
                            int* __restrict__ bcur, int* __restrict__ ebuf, int E) {
    __shared__ int hist[200];
    __shared__ int basebkt[200];
    const int tid = threadIdx.x;
    if (tid < 200) hist[tid] = 0;
    __syncthreads();
    const int e0 = blockIdx.x * EPB, e1 = min(e0 + EPB, E);
    for (int e = e0 + tid; e < e1; e += 256) atomicAdd(&hist[dst[e] >> 9], 1);
    __syncthreads();
    if (tid < NBUCKET) {
        int h = hist[tid];
        basebkt[tid] = tid * CAP + (h ? atomicAdd(&bcur[tid], h) : 0);
    }
    __syncthreads();
    if (tid < 200) hist[tid] = 0;
    __syncthreads();
    for (int e = e0 + tid; e < e1; e += 256) {
        int d = dst[e];
        int bk = d >> 9;
        int o = atomicAdd(&hist[bk], 1);
        ebuf[basebkt[bk] + o] = (src[e] << 9) | (d & 511);
    }
}

// ---------------- per-bucket counting sort -> deg, stv, dinv, adj (bucketed layout)
__launch_bounds__(256)
__global__ void k_bsort(const int* __restrict__ ebuf, const int* __restrict__ bcur,
                        int* __restrict__ adj, int* __restrict__ stv,
                        int* __restrict__ deg, float* __restrict__ dinv, int N) {
    __shared__ int cnt[512];
    __shared__ int offs[512];
    const int b = blockIdx.x;
    const int tid = threadIdx.x;
    const int base = b * CAP;
    const int n_b = min(bcur[b], CAP);
    const int node0 = b << 9;
    cnt[tid] = 0; cnt[tid + 256] = 0;
    __syncthreads();
    for (int i = tid; i < n_b; i += 256)
        atomicAdd(&cnt[ebuf[base + i] & 511], 1);
    __syncthreads();
    if (tid < 64) {  // wave-0 exclusive scan of 512
        int v[8], tot = 0;
#pragma unroll
        for (int j = 0; j < 8; ++j) { int t = cnt[tid * 8 + j]; v[j] = tot; tot += t; }
        int inc = tot;
#pragma unroll
        for (int d = 1; d < 64; d <<= 1) {
            int u = __shfl_up(inc, d, 64);
            if (tid >= d) inc += u;
        }
        const int excl = inc - tot;
#pragma unroll
        for (int j = 0; j < 8; ++j) offs[tid * 8 + j] = excl + v[j];
    }
    __syncthreads();
#pragma unroll
    for (int h = 0; h < 2; ++h) {
        int local = tid + h * 256;
        int node = node0 + local;
        if (node < N) {
            stv[node] = base + offs[local];
            deg[node] = cnt[local];
            dinv[node] = rsqrtf((float)(cnt[local] + 1));
        }
    }
    __syncthreads();
    for (int i = tid; i < n_b; i += 256) {  // offs doubles as cursor
        int pk = ebuf[base + i];
        int pos = atomicAdd(&offs[pk & 511], 1);
        adj[base + pos] = pk >> 9;
    }
}

// ---------------- all three W -> fp16 B-fragment swizzles + bCur zeroing
__global__ void k_wswz_all(const float* __restrict__ W1, const float* __restrict__ W2,
                           const float* __restrict__ W3, _Float16* __restrict__ wz1,
                           _Float16* __restrict__ wz2, _Float16* __restrict__ wz3,
                           int* __restrict__ bcur) {
    if (blockIdx.x == 0) bcur[threadIdx.x] = 0;   // 256 ints
    int t = blockIdx.x * 256 + threadIdx.x;
    const float* W; _Float16* wsz; int BN;
    if (t < 2048)      { W = W1; wsz = wz1; BN = 128; }
    else if (t < 4096) { W = W2; wsz = wz2; BN = 128; t -= 2048; }
    else if (t < 5120) { W = W3; wsz = wz3; BN = 64;  t -= 4096; }
    else return;
    const int l = t & 63;
    const int kblk = (t >> 6) & 3;
    const int nt = t >> 8;
    const int krow = kblk * 32 + ((l >> 4) << 3);
    const int col = nt * 16 + (l & 15);
    _Float16 v[8];
#pragma unroll
    for (int j = 0; j < 8; ++j) v[j] = (_Float16)W[(krow + j) * BN + col];
    *(uint4*)&wsz[t << 3] = *(uint4*)v;
}

// ---------------- MFMA GEMM: tp[i][:] = fp16( dinv[i] * (X[i][:] @ W) ), K=128
template <int BN, bool AFP16>
__launch_bounds__(256, 4)
__global__ void k_gemm_mfma(const void* __restrict__ Xv, const _Float16* __restrict__ wsz,
                            const float* __restrict__ dinv, __half* __restrict__ out, int N) {
    constexpr int NT = BN / 16;
    constexpr int PAD = 8;
    __shared__ __align__(16) _Float16 smem[BN * 128];  // B frags; reused for epilogue

    const int tid = threadIdx.x;
    for (int i = tid; i < BN * 16; i += 256)
        *(uint4*)&smem[i << 3] = *(const uint4*)&wsz[i << 3];

    const int w = tid >> 6;
    const int lane = tid & 63;
    const int q = lane >> 4;
    const int m = lane & 15;
    const int row0 = blockIdx.x * 64;
    const int arow = row0 + w * 16 + m;
    const int arowc = arow < N ? arow : N - 1;

    float4v acc[NT];
#pragma unroll
    for (int nt = 0; nt < NT; ++nt) acc[nt] = (float4v){0.f, 0.f, 0.f, 0.f};

    __syncthreads();

#pragma unroll
    for (int kblk = 0; kblk < 4; ++kblk) {
        half8 af;
        if constexpr (AFP16) {
            const _Float16* A = (const _Float16*)Xv + (size_t)arowc * 128 + (q << 3);
            af = *(const half8*)(A + kblk * 32);
        } else {
            const float* A = (const float*)Xv + (size_t)arowc * 128 + (q << 3);
            float4 a0 = *(const float4*)(A + kblk * 32);
            float4 a1 = *(const float4*)(A + kblk * 32 + 4);
            af[0] = (_Float16)a0.x; af[1] = (_Float16)a0.y;
            af[2] = (_Float16)a0.z; af[3] = (_Float16)a0.w;
            af[4] = (_Float16)a1.x; af[5] = (_Float16)a1.y;
            af[6] = (_Float16)a1.z; af[7] = (_Float16)a1.w;
        }
#pragma unroll
        for (int nt = 0; nt < NT; ++nt) {
            half8 bf = *(const half8*)&smem[(((nt << 2) + kblk) << 9) + (lane << 3)];
            acc[nt] = __builtin_amdgcn_mfma_f32_16x16x32_f16(af, bf, acc[nt], 0, 0, 0);
        }
    }

    float s[4];
#pragma unroll
    for (int r = 0; r < 4; ++r) {
        int rr = row0 + w * 16 + q * 4 + r;
        s[r] = dinv[rr < N ? rr : N - 1];
    }
    __syncthreads();  // all B reads done before smem reuse
    _Float16* eb = smem;
#pragma unroll
    for (int nt = 0; nt < NT; ++nt)
#pragma unroll
        for (int r = 0; r < 4; ++r)
            eb[(w * 16 + q * 4 + r) * (BN + PAD) + nt * 16 + m] = (_Float16)(acc[nt][r] * s[r]);
    __syncthreads();
    constexpr int CPR = BN / 8;
    for (int i = tid; i < 64 * CPR; i += 256) {
        int row = i / CPR;
        int cf = (i % CPR) * 8;
        if (row0 + row < N)
            *(uint4*)&out[(size_t)(row0 + row) * BN + cf] = *(uint4*)&eb[row * (BN + PAD) + cf];
    }
}

// ---------------- d=128 aggregation: 4 edges per wave-load
// 4 groups of 16 lanes; group g handles edge e+g; each lane loads uint4 (8 cols).
template <bool RELU>
__launch_bounds__(256)
__global__ void k_agg128(const __half* __restrict__ tp, const int* __restrict__ adj,
                         const int* __restrict__ startv, const int* __restrict__ deg,
                         const float* __restrict__ dinv, const float* __restrict__ bias,
                         _Float16* __restrict__ out, int N) {
    const int node = (blockIdx.x << 2) + (threadIdx.x >> 6);
    const int lane = threadIdx.x & 63;
    if (node >= N) return;
    const int s = startv[node];
    const int cnt = deg[node];
    const float di = dinv[node];
    const int g = lane >> 4;        // edge group 0..3
    const int sl = lane & 15;       // 16 B chunk within row
    const uint4* rowb = (const uint4*)tp;   // row stride = 16 uint4 (256 B)

    float acc[8] = {0.f, 0.f, 0.f, 0.f, 0.f, 0.f, 0.f, 0.f};
    auto addrow = [&](uint4 v) {
        float2 f0 = __half22float2(*(__half2*)&v.x);
        float2 f1 = __half22float2(*(__half2*)&v.y);
        float2 f2 = __half22float2(*(__half2*)&v.z);
        float2 f3 = __half22float2(*(__half2*)&v.w);
        acc[0] += f0.x; acc[1] += f0.y; acc[2] += f1.x; acc[3] += f1.y;
        acc[4] += f2.x; acc[5] += f2.y; acc[6] += f3.x; acc[7] += f3.y;
    };
    if (g == 0) addrow(rowb[(size_t)node * 16 + sl]);   // self-loop once

    int e = 0;
    for (; e + 16 <= cnt; e += 16) {
        int j[4];
#pragma unroll
        for (int u = 0; u < 4; ++u) j[u] = adj[s + e + 4 * u + g];
        uint4 v[4];
#pragma unroll
        for (int u = 0; u < 4; ++u) v[u] = rowb[(size_t)j[u] * 16 + sl];
#pragma unroll
        for (int u = 0; u < 4; ++u) addrow(v[u]);
    }
    for (; e + 4 <= cnt; e += 4)
        addrow(rowb[(size_t)adj[s + e + g] * 16 + sl]);
    if (e + g < cnt)
        addrow(rowb[(size_t)adj[s + e + g] * 16 + sl]);

#pragma unroll
    for (int i = 0; i < 8; ++i) {
        acc[i] += __shfl_xor(acc[i], 32);
        acc[i] += __shfl_xor(acc[i], 16);
    }
    if (g == 0) {
        float4 b0 = *(const float4*)&bias[sl * 8];
        float4 b1 = *(const float4*)&bias[sl * 8 + 4];
        float o[8];
        o[0] = di * acc[0] + b0.x; o[1] = di * acc[1] + b0.y;
        o[2] = di * acc[2] + b0.z; o[3] = di * acc[3] + b0.w;
        o[4] = di * acc[4] + b1.x; o[5] = di * acc[5] + b1.y;
        o[6] = di * acc[6] + b1.z; o[7] = di * acc[7] + b1.w;
        if (RELU)
#pragma unroll
            for (int i = 0; i < 8; ++i) o[i] = fmaxf(o[i], 0.f);
        __half2 ov[4];
#pragma unroll
        for (int i = 0; i < 4; ++i) ov[i] = __floats2half2_rn(o[2 * i], o[2 * i + 1]);
        *(uint4*)&out[(size_t)node * 128 + sl * 8] = *(uint4*)ov;
    }
}

// ---------------- d=64 aggregation (fp32 out): 4 edges per wave-load
__launch_bounds__(256)
__global__ void k_agg64(const __half* __restrict__ tp, const int* __restrict__ adj,
                        const int* __restrict__ startv, const int* __restrict__ deg,
                        const float* __restrict__ dinv, const float* __restrict__ bias,
                        float* __restrict__ out, int N) {
    const int node = (blockIdx.x << 2) + (threadIdx.x >> 6);
    const int lane = threadIdx.x & 63;
    if (node >= N) return;
    const int s = startv[node];
    const int cnt = deg[node];
    const float di = dinv[node];
    const int g = lane >> 4;
    const int sl = lane & 15;
    const uint2* rowb = (const uint2*)tp;   // row stride = 16 uint2 (128 B)

    float acc[4] = {0.f, 0.f, 0.f, 0.f};
    auto addrow = [&](uint2 v) {
        float2 f0 = __half22float2(*(__half2*)&v.x);
        float2 f1 = __half22float2(*(__half2*)&v.y);
        acc[0] += f0.x; acc[1] += f0.y; acc[2] += f1.x; acc[3] += f1.y;
    };
    if (g == 0) addrow(rowb[(size_t)node * 16 + sl]);   // self-loop

    int e = 0;
    for (; e + 16 <= cnt; e += 16) {
        int j[4];
#pragma unroll
        for (int u = 0; u < 4; ++u) j[u] = adj[s + e + 4 * u + g];
        uint2 v[4];
#pragma unroll
        for (int u = 0; u < 4; ++u) v[u] = rowb[(size_t)j[u] * 16 + sl];
#pragma unroll
        for (int u = 0; u < 4; ++u) addrow(v[u]);
    }
    for (; e + 4 <= cnt; e += 4)
        addrow(rowb[(size_t)adj[s + e + g] * 16 + sl]);
    if (e + g < cnt)
        addrow(rowb[(size_t)adj[s + e + g] * 16 + sl]);

#pragma unroll
    for (int i = 0; i < 4; ++i) {
        acc[i] += __shfl_xor(acc[i], 32);
        acc[i] += __shfl_xor(acc[i], 16);
    }
    if (g == 0) {
        float4 bb = *(const float4*)&bias[sl * 4];
        float4 o;
        o.x = di * acc[0] + bb.x; o.y = di * acc[1] + bb.y;
        o.z = di * acc[2] + bb.z; o.w = di * acc[3] + bb.w;
        *(float4*)&out[(size_t)node * 64 + sl * 4] = o;
    }
}

extern "C" void kernel_launch(void* const* d_in, const int* in_sizes, int n_in,
                              void* d_out, int out_size, void* d_ws, size_t ws_size,
                              hipStream_t stream) {
    const float* x  = (const float*)d_in[0];
    const int*   ei = (const int*)d_in[1];
    const float* W1 = (const float*)d_in[2];
    const float* b1 = (const float*)d_in[3];
    const float* W2 = (const float*)d_in[4];
    const float* b2 = (const float*)d_in[5];
    const float* W3 = (const float*)d_in[6];
    const float* b3 = (const float*)d_in[7];
    float* out = (float*)d_out;
    const int* src = ei;            // edge_index[0]
    const int* dst = ei + N_EDGES;  // edge_index[1]

    char* p = (char*)d_ws;
    __half* tp      = (__half*)p;    p += (size_t)N_NODES * 128 * 2;   // 25.6 MB
    _Float16* hbuf  = (_Float16*)p;  p += (size_t)N_NODES * 128 * 2;   // 25.6 MB
    int*   deg  = (int*)p;    p += (size_t)N_NODES * 4;
    float* dinv = (float*)p;  p += (size_t)N_NODES * 4;
    int*   stv  = (int*)p;    p += (size_t)N_NODES * 4;
    int*   bCur = (int*)p;    p += 1024;                               // bucket fill counts
    int*   adj  = (int*)p;    p += (size_t)NBUCKET * CAP * 4 + 16384;  // 7.0 MB bucketed
    _Float16* wz1 = (_Float16*)p; p += 16384 * 2;                      // 32 KB
    _Float16* wz2 = (_Float16*)p; p += 16384 * 2;                      // 32 KB
    _Float16* wz3 = (_Float16*)p; p += 8192 * 2;                       // 16 KB
    size_t need = (size_t)(p - (char*)d_ws);
    if (ws_size < need) return;  // visible failure rather than OOB

    int* ebuf = (int*)tp;  // 7.0 MB alias; tp not live until layer-1 GEMM

    k_wswz_all<<<20, 256, 0, stream>>>(W1, W2, W3, wz1, wz2, wz3, bCur);
    k_partition<<<256, 256, 0, stream>>>(src, dst, bCur, ebuf, N_EDGES);
    k_bsort<<<NBUCKET, 256, 0, stream>>>(ebuf, bCur, adj, stv, deg, dinv, N_NODES);

    const int gb = (N_NODES + 63) / 64;
    const int ab = (N_NODES + 3) / 4;
    // layer 1: relu(agg(x@W1) + b1) -> fp16 hbuf
    k_gemm_mfma<128, false><<<gb, 256, 0, stream>>>(x, wz1, dinv, tp, N_NODES);
    k_agg128<true><<<ab, 256, 0, stream>>>(tp, adj, stv, deg, dinv, b1, hbuf, N_NODES);
    // layer 2
    k_gemm_mfma<128, true><<<gb, 256, 0, stream>>>(hbuf, wz2, dinv, tp, N_NODES);
    k_agg128<true><<<ab, 256, 0, stream>>>(tp, adj, stv, deg, dinv, b2, hbuf, N_NODES);
    // layer 3: agg(h@W3) + b3 (no relu) -> fp32 out
    k_gemm_mfma<64, true><<<gb, 256, 0, stream>>>(hbuf, wz3, dinv, tp, N_NODES);
    k_agg64<<<ab, 256, 0, stream>>>(tp, adj, stv, deg, dinv, b3, out, N_NODES);
}